// Round 1
// baseline (219.680 us; speedup 1.0000x reference)
//
#include <hip/hip_runtime.h>
#include <math.h>

// TransferNet: BSZ=8, E=40000, D=128, R=512, NUM_STEPS=2, K=3, DEG=64
#define BSZ 8
#define E_ENT 40000
#define D_DIM 128
#define NUM_STEPS 2
#define K_TOP 3
#define DEG 64
#define M_TRI (K_TOP * DEG)   // 192
#define D3 (3 * D_DIM)        // 384

__device__ __forceinline__ float sigmoidf_(float x) { return 1.0f / (1.0f + expf(-x)); }

// One-time transpose of GRU weights: W [384][128] row-major -> WT [128][384]
// so the step kernel's inner loop reads WT[kk*384 + d] coalesced across d.
__global__ void transpose_kernel(const float* __restrict__ W_ih,
                                 const float* __restrict__ W_hh,
                                 float* __restrict__ WT_ih,
                                 float* __restrict__ WT_hh) {
    int i = blockIdx.x * blockDim.x + threadIdx.x;
    if (i >= D3 * D_DIM) return;
    int row = i / D_DIM, col = i % D_DIM;
    WT_ih[col * D3 + row] = W_ih[row * D_DIM + col];
    WT_hh[col * D3 + row] = W_hh[row * D_DIM + col];
}

// cq[t][b][d] = tanh( (rel_emb[query[b]] @ step_W[t])[d] + step_b[t][d] )
__global__ void cq_kernel(const float* __restrict__ rel_emb,
                          const float* __restrict__ step_W,
                          const float* __restrict__ step_b,
                          const int* __restrict__ query,
                          float* __restrict__ cq) {
    int t = blockIdx.x / BSZ, b = blockIdx.x % BSZ;
    int d = threadIdx.x;
    __shared__ float xs[D_DIM];
    xs[d] = rel_emb[query[b] * D_DIM + d];
    __syncthreads();
    float acc = step_b[t * D_DIM + d];
    const float* W = step_W + t * D_DIM * D_DIM;
    for (int k = 0; k < D_DIM; k++) acc += xs[k] * W[k * D_DIM + d];
    cq[(t * BSZ + b) * D_DIM + d] = tanhf(acc);
}

// Top-3 per row with jax.lax.top_k tie-break (equal value -> lower index).
// Values are >= 0, so float bits are monotone; key = (bits<<32) | (~idx).
__global__ void topk_kernel(const float* __restrict__ e,
                            int* __restrict__ out_idx,
                            float* __restrict__ out_val) {
    int b = blockIdx.x;
    int tid = threadIdx.x;
    const float* row = e + (size_t)b * E_ENT;
    __shared__ unsigned long long red[256];
    __shared__ int picked[K_TOP];
    for (int p = 0; p < K_TOP; p++) {
        unsigned long long best = 0ull;  // decodes to v=0, idx=-1: beaten by any real elem
        for (int i = tid; i < E_ENT; i += 256) {
            bool skip = false;
            for (int q = 0; q < p; q++) if (picked[q] == i) skip = true;
            if (skip) continue;
            unsigned int vb = __float_as_uint(row[i]);
            unsigned long long key = ((unsigned long long)vb << 32) |
                                     (unsigned long long)(0xFFFFFFFFu - (unsigned int)i);
            if (key > best) best = key;
        }
        red[tid] = best;
        __syncthreads();
        for (int s = 128; s > 0; s >>= 1) {
            if (tid < s && red[tid + s] > red[tid]) red[tid] = red[tid + s];
            __syncthreads();
        }
        if (tid == 0) {
            unsigned long long key = red[0];
            int idx = (int)(0xFFFFFFFFu - (unsigned int)(key & 0xFFFFFFFFull));
            picked[p] = idx;
            out_idx[b * K_TOP + p] = idx;
            out_val[b * K_TOP + p] = __uint_as_float((unsigned int)(key >> 32));
        }
        __syncthreads();
    }
}

// One block per (b, k, edge). 128 threads = one GRU cell (dim d per thread).
// sub_p comes from top_val (sub == picked entity by KB construction).
// hist is kept sparse: prev step's (obj, feat) records; sub_feat = sum of
// matching records. Writes: atomicAdd obj_p into e_out; at t==0 also stores
// this step's (obj, feat=trans*obj_p) records for the next step.
__global__ void step_kernel(int t,
                            const int* __restrict__ top_idx,
                            const float* __restrict__ top_val,
                            const float* __restrict__ cq,      // [BSZ][D] slice for this t
                            const float* __restrict__ rel_emb,
                            const int* __restrict__ kb_triple,
                            const int* __restrict__ kb_range,
                            const float* __restrict__ WT_ih,
                            const float* __restrict__ WT_hh,
                            const float* __restrict__ b_ih,
                            const float* __restrict__ b_hh,
                            const float* __restrict__ cls_w,
                            const float* __restrict__ cls_b,
                            const float* __restrict__ feat_in,
                            const int* __restrict__ obj_in,
                            float* __restrict__ feat_out,
                            int* __restrict__ obj_out,
                            float* __restrict__ e_out) {
    int blk = blockIdx.x;
    int b = blk / (K_TOP * DEG);
    int rem = blk % (K_TOP * DEG);
    int k = rem / DEG;
    int j = rem % DEG;
    int d = threadIdx.x;

    int ent = top_idx[b * K_TOP + k];
    float sub_p = top_val[b * K_TOP + k];
    int lo = kb_range[2 * ent], hi = kb_range[2 * ent + 1];
    int tri = lo + j;
    bool vj = (tri < hi) && (t > 0 || k == 0);  // ent_mask: n_valid=1 at step 0
    int tuse = vj ? tri : 0;
    int sub = kb_triple[3 * tuse + 0];
    int obj = kb_triple[3 * tuse + 1];
    int rel = kb_triple[3 * tuse + 2];

    __shared__ float xs[D_DIM];
    __shared__ float hs[D_DIM];
    __shared__ float red[D_DIM];

    xs[d] = rel_emb[rel * D_DIM + d];
    float hd = 0.f;
    if (t > 0) {
        const int* ob = obj_in + b * M_TRI;
        const float* fb = feat_in + (size_t)b * M_TRI * D_DIM;
        for (int m = 0; m < M_TRI; m++) {
            if (ob[m] == sub) hd += fb[m * D_DIM + d];
        }
    }
    hs[d] = hd;
    __syncthreads();

    float ir = b_ih[d], iz = b_ih[D_DIM + d], inn = b_ih[2 * D_DIM + d];
    float hr = b_hh[d], hz = b_hh[D_DIM + d], hn = b_hh[2 * D_DIM + d];
    if (t > 0) {
        for (int kk = 0; kk < D_DIM; kk++) {
            float xk = xs[kk], hk = hs[kk];
            const float* wi = WT_ih + kk * D3;
            const float* wh = WT_hh + kk * D3;
            ir += xk * wi[d]; iz += xk * wi[D_DIM + d]; inn += xk * wi[2 * D_DIM + d];
            hr += hk * wh[d]; hz += hk * wh[D_DIM + d]; hn += hk * wh[2 * D_DIM + d];
        }
    } else {  // h == 0 at step 0: skip the W_hh dots (gh = b_hh)
        for (int kk = 0; kk < D_DIM; kk++) {
            float xk = xs[kk];
            const float* wi = WT_ih + kk * D3;
            ir += xk * wi[d]; iz += xk * wi[D_DIM + d]; inn += xk * wi[2 * D_DIM + d];
        }
    }
    float r = sigmoidf_(ir + hr);
    float z = sigmoidf_(iz + hz);
    float n = tanhf(inn + r * hn);
    float trans = (1.f - z) * n + z * hd;

    red[d] = trans * cq[b * D_DIM + d] * cls_w[d];
    __syncthreads();
    for (int s = 64; s > 0; s >>= 1) {
        if (d < s) red[d] += red[d + s];
        __syncthreads();
    }
    float prob = sigmoidf_(red[0] + cls_b[0]);
    float obj_p = vj ? sub_p * prob : 0.f;

    if (t == 0) {
        feat_out[((size_t)b * M_TRI + rem) * D_DIM + d] = trans * obj_p;
        if (d == 0) obj_out[b * M_TRI + rem] = obj;
    }
    if (d == 0 && obj_p != 0.f) atomicAdd(&e_out[(size_t)b * E_ENT + obj], obj_p);
}

// last_e = last_e / max(last_e, 1)  (elementwise)
__global__ void norm_kernel(float* __restrict__ e) {
    int i = blockIdx.x * blockDim.x + threadIdx.x;
    if (i < BSZ * E_ENT) {
        float v = e[i];
        e[i] = v / (v > 1.0f ? v : 1.0f);
    }
}

extern "C" void kernel_launch(void* const* d_in, const int* in_sizes, int n_in,
                              void* d_out, int out_size, void* d_ws, size_t ws_size,
                              hipStream_t stream) {
    const float* start    = (const float*)d_in[0];
    const float* rel_emb  = (const float*)d_in[1];
    const float* step_W   = (const float*)d_in[2];
    const float* step_b   = (const float*)d_in[3];
    const float* W_ih     = (const float*)d_in[4];
    const float* W_hh     = (const float*)d_in[5];
    const float* b_ih     = (const float*)d_in[6];
    const float* b_hh     = (const float*)d_in[7];
    const float* cls_w    = (const float*)d_in[8];
    const float* cls_b    = (const float*)d_in[9];
    const int*   query    = (const int*)d_in[10];
    const int*   kb_triple = (const int*)d_in[11];
    const int*   kb_range  = (const int*)d_in[12];
    float* out = (float*)d_out;

    char* ws = (char*)d_ws;
    float* WT_ih = (float*)ws;  ws += (size_t)D3 * D_DIM * sizeof(float);
    float* WT_hh = (float*)ws;  ws += (size_t)D3 * D_DIM * sizeof(float);
    float* cq    = (float*)ws;  ws += (size_t)NUM_STEPS * BSZ * D_DIM * sizeof(float);
    float* feat  = (float*)ws;  ws += (size_t)BSZ * M_TRI * D_DIM * sizeof(float);
    int*   objs  = (int*)ws;    ws += (size_t)BSZ * M_TRI * sizeof(int);
    int*   idx0  = (int*)ws;    ws += (size_t)BSZ * K_TOP * sizeof(int);
    float* val0  = (float*)ws;  ws += (size_t)BSZ * K_TOP * sizeof(float);
    int*   idx1  = (int*)ws;    ws += (size_t)BSZ * K_TOP * sizeof(int);
    float* val1  = (float*)ws;  ws += (size_t)BSZ * K_TOP * sizeof(float);

    transpose_kernel<<<(D3 * D_DIM + 255) / 256, 256, 0, stream>>>(W_ih, W_hh, WT_ih, WT_hh);
    cq_kernel<<<NUM_STEPS * BSZ, D_DIM, 0, stream>>>(rel_emb, step_W, step_b, query, cq);

    // ---- step 0 ----
    topk_kernel<<<BSZ, 256, 0, stream>>>(start, idx0, val0);
    hipMemsetAsync(d_out, 0, (size_t)BSZ * E_ENT * sizeof(float), stream);
    step_kernel<<<BSZ * K_TOP * DEG, D_DIM, 0, stream>>>(
        0, idx0, val0, cq, rel_emb, kb_triple, kb_range,
        WT_ih, WT_hh, b_ih, b_hh, cls_w, cls_b,
        nullptr, nullptr, feat, objs, out);
    norm_kernel<<<(BSZ * E_ENT + 255) / 256, 256, 0, stream>>>(out);

    // ---- step 1 ----
    topk_kernel<<<BSZ, 256, 0, stream>>>(out, idx1, val1);
    hipMemsetAsync(d_out, 0, (size_t)BSZ * E_ENT * sizeof(float), stream);
    step_kernel<<<BSZ * K_TOP * DEG, D_DIM, 0, stream>>>(
        1, idx1, val1, cq + BSZ * D_DIM, rel_emb, kb_triple, kb_range,
        WT_ih, WT_hh, b_ih, b_hh, cls_w, cls_b,
        feat, objs, nullptr, nullptr, out);
    norm_kernel<<<(BSZ * E_ENT + 255) / 256, 256, 0, stream>>>(out);
}

// Round 2
// 63.988 us; speedup vs baseline: 3.4331x; 3.4331x over previous
//
#include <hip/hip_runtime.h>
#include <math.h>

// TransferNet: BSZ=8, E=40000, D=128, R=512, NUM_STEPS=2, K=3, DEG=64
#define BSZ 8
#define E_ENT 40000
#define D_DIM 128
#define K_TOP 3
#define DEG 64
#define D3 (3 * D_DIM)   // 384
#define NCH 40           // chunks per row for dense topk
#define CHUNK 1000       // NCH * CHUNK == E_ENT

typedef unsigned long long ull;

__device__ __forceinline__ float sigmoidf_(float x) { return 1.0f / (1.0f + expf(-x)); }

// Key encoding preserves jax.lax.top_k order for v >= 0:
// primary value descending (float bits monotone for v>=0), tie -> lower index.
__device__ __forceinline__ ull make_key(float v, int idx) {
    return ((ull)__float_as_uint(v) << 32) |
           (ull)(0xFFFFFFFFu - (unsigned int)idx);
}

// One-time transpose of GRU weights: W [384][128] -> WT [128][384]
__global__ void transpose_kernel(const float* __restrict__ W_ih,
                                 const float* __restrict__ W_hh,
                                 float* __restrict__ WT_ih,
                                 float* __restrict__ WT_hh) {
    int i = blockIdx.x * blockDim.x + threadIdx.x;
    if (i >= D3 * D_DIM) return;
    int row = i / D_DIM, col = i % D_DIM;
    WT_ih[col * D3 + row] = W_ih[row * D_DIM + col];
    WT_hh[col * D3 + row] = W_hh[row * D_DIM + col];
}

// cq[t][b][d] = tanh( (rel_emb[query[b]] @ step_W[t])[d] + step_b[t][d] )
__global__ void cq_kernel(const float* __restrict__ rel_emb,
                          const float* __restrict__ step_W,
                          const float* __restrict__ step_b,
                          const int* __restrict__ query,
                          float* __restrict__ cq) {
    int t = blockIdx.x / BSZ, b = blockIdx.x % BSZ;
    int d = threadIdx.x;
    __shared__ float xs[D_DIM];
    xs[d] = rel_emb[query[b] * D_DIM + d];
    __syncthreads();
    float acc = step_b[t * D_DIM + d];
    const float* W = step_W + t * D_DIM * D_DIM;
    for (int k = 0; k < D_DIM; k++) acc += xs[k] * W[k * D_DIM + d];
    cq[(t * BSZ + b) * D_DIM + d] = tanhf(acc);
}

// Dense top-3, stage A: one block per (row, chunk of 1000). Emits the chunk's
// local top-3 keys. Union of per-chunk top-3 contains the global top-3.
__global__ void topk_stageA(const float* __restrict__ e, ull* __restrict__ keys) {
    int blk = blockIdx.x;
    int b = blk / NCH, c = blk % NCH;
    int tid = threadIdx.x;
    const float* row = e + (size_t)b * E_ENT;
    int base = c * CHUNK;
    __shared__ ull red[256];
    __shared__ ull pick[K_TOP];
    for (int p = 0; p < K_TOP; p++) {
        ull best = 0ull;
        for (int i = tid; i < CHUNK; i += 256) {
            int idx = base + i;
            ull k = make_key(row[idx], idx);
            bool skip = false;
            for (int q = 0; q < p; q++) if (pick[q] == k) skip = true;
            if (!skip && k > best) best = k;
        }
        red[tid] = best;
        __syncthreads();
        for (int s = 128; s > 0; s >>= 1) {
            if (tid < s && red[tid + s] > red[tid]) red[tid] = red[tid + s];
            __syncthreads();
        }
        if (tid == 0) { pick[p] = red[0]; keys[(b * NCH + c) * K_TOP + p] = red[0]; }
        __syncthreads();
    }
}

// Dense top-3, stage B: reduce NCH*3 = 120 candidate keys per row.
__global__ void topk_stageB(const ull* __restrict__ keys,
                            int* __restrict__ out_idx, float* __restrict__ out_val) {
    int b = blockIdx.x, tid = threadIdx.x;  // 128 threads
    __shared__ ull sk[NCH * K_TOP];
    __shared__ ull red[128];
    __shared__ ull pick[K_TOP];
    if (tid < NCH * K_TOP) sk[tid] = keys[b * NCH * K_TOP + tid];
    __syncthreads();
    for (int p = 0; p < K_TOP; p++) {
        ull best = 0ull;
        if (tid < NCH * K_TOP) {
            ull k = sk[tid];
            bool skip = false;
            for (int q = 0; q < p; q++) if (pick[q] == k) skip = true;
            if (!skip) best = k;
        }
        red[tid] = best;
        __syncthreads();
        for (int s = 64; s > 0; s >>= 1) {
            if (tid < s && red[tid + s] > red[tid]) red[tid] = red[tid + s];
            __syncthreads();
        }
        if (tid == 0) {
            pick[p] = red[0];
            out_idx[b * K_TOP + p] = (int)(0xFFFFFFFFu - (unsigned int)(red[0] & 0xFFFFFFFFull));
            out_val[b * K_TOP + p] = __uint_as_float((unsigned int)(red[0] >> 32));
        }
        __syncthreads();
    }
}

// Sparse top-3 over step-0's <=64 (obj, p) records. Aggregates duplicate
// objects (ascending-m order == jax scatter-add order), normalizes by
// max(v,1), then 3-pass exclusion top-k with the same tie-break key.
// Zero-valued picks contribute exactly zero downstream, so their indices
// only need to be in range.
__global__ void cand_topk(const int* __restrict__ objs, const float* __restrict__ p0,
                          int* __restrict__ out_idx, float* __restrict__ out_val) {
    int b = blockIdx.x, m = threadIdx.x;  // 64 threads
    __shared__ int so[DEG];
    __shared__ float sp[DEG];
    __shared__ ull red[DEG];
    __shared__ int picked[K_TOP];
    so[m] = objs[b * DEG + m];
    sp[m] = p0[b * DEG + m];
    __syncthreads();
    int o = so[m];
    float v = 0.f;
    for (int i = 0; i < DEG; i++) if (so[i] == o) v += sp[i];
    v = v / fmaxf(v, 1.0f);
    ull key = make_key(v, o);
    for (int p = 0; p < K_TOP; p++) {
        ull k2 = key;
        for (int q = 0; q < p; q++) if (picked[q] == o) k2 = 0ull;
        red[m] = k2;
        __syncthreads();
        for (int s = 32; s > 0; s >>= 1) {
            if (m < s && red[m + s] > red[m]) red[m] = red[m + s];
            __syncthreads();
        }
        if (m == 0) {
            ull best = red[0];
            int idx = (int)(0xFFFFFFFFu - (unsigned int)(best & 0xFFFFFFFFull));
            float val = __uint_as_float((unsigned int)(best >> 32));
            if (idx < 0 || idx >= E_ENT) { idx = p; val = 0.f; }  // degenerate guard
            picked[p] = idx;
            out_idx[b * K_TOP + p] = idx;
            out_val[b * K_TOP + p] = val;
        }
        __syncthreads();
    }
}

// One block per (b, k, edge); 128 threads = one GRU cell.
// t==0 (nk=1): emit (obj, obj_p, feat = trans*obj_p) records, no dense write.
// t==1 (nk=3): hist lookup = match-and-sum over step-0 records; atomicAdd
// obj_p into dense e_out.
__global__ void step_kernel(int t, int nk,
                            const int* __restrict__ top_idx,
                            const float* __restrict__ top_val,
                            const float* __restrict__ cq,  // [BSZ][D] for this t
                            const float* __restrict__ rel_emb,
                            const int* __restrict__ kb_triple,
                            const int* __restrict__ kb_range,
                            const float* __restrict__ WT_ih,
                            const float* __restrict__ WT_hh,
                            const float* __restrict__ b_ih,
                            const float* __restrict__ b_hh,
                            const float* __restrict__ cls_w,
                            const float* __restrict__ cls_b,
                            const float* __restrict__ feat_in,
                            const int* __restrict__ obj_in,
                            float* __restrict__ feat_out,
                            int* __restrict__ obj_out,
                            float* __restrict__ p_out,
                            float* __restrict__ e_out) {
    int blk = blockIdx.x;
    int b = blk / (nk * DEG);
    int rem = blk % (nk * DEG);
    int k = rem / DEG;
    int j = rem % DEG;
    int d = threadIdx.x;

    int ent = top_idx[b * K_TOP + k];
    float sub_p = top_val[b * K_TOP + k];
    int lo = kb_range[2 * ent], hi = kb_range[2 * ent + 1];
    int tri = lo + j;
    bool vj = (tri < hi);
    int tuse = vj ? tri : 0;
    int sub = kb_triple[3 * tuse + 0];
    int obj = kb_triple[3 * tuse + 1];
    int rel = kb_triple[3 * tuse + 2];

    __shared__ float xs[D_DIM];
    __shared__ float hs[D_DIM];
    __shared__ float red[D_DIM];

    xs[d] = rel_emb[rel * D_DIM + d];
    float hd = 0.f;
    if (t > 0) {
        const int* ob = obj_in + b * DEG;
        const float* fb = feat_in + (size_t)b * DEG * D_DIM;
        for (int m = 0; m < DEG; m++) {
            if (ob[m] == sub) hd += fb[m * D_DIM + d];
        }
    }
    hs[d] = hd;
    __syncthreads();

    float ir = b_ih[d], iz = b_ih[D_DIM + d], inn = b_ih[2 * D_DIM + d];
    float hr = b_hh[d], hz = b_hh[D_DIM + d], hn = b_hh[2 * D_DIM + d];
    if (t > 0) {
        for (int kk = 0; kk < D_DIM; kk++) {
            float xk = xs[kk], hk = hs[kk];
            const float* wi = WT_ih + kk * D3;
            const float* wh = WT_hh + kk * D3;
            ir += xk * wi[d]; iz += xk * wi[D_DIM + d]; inn += xk * wi[2 * D_DIM + d];
            hr += hk * wh[d]; hz += hk * wh[D_DIM + d]; hn += hk * wh[2 * D_DIM + d];
        }
    } else {  // h == 0 at step 0: gh = b_hh
        for (int kk = 0; kk < D_DIM; kk++) {
            float xk = xs[kk];
            const float* wi = WT_ih + kk * D3;
            ir += xk * wi[d]; iz += xk * wi[D_DIM + d]; inn += xk * wi[2 * D_DIM + d];
        }
    }
    float r = sigmoidf_(ir + hr);
    float z = sigmoidf_(iz + hz);
    float n = tanhf(inn + r * hn);
    float trans = (1.f - z) * n + z * hd;

    red[d] = trans * cq[b * D_DIM + d] * cls_w[d];
    __syncthreads();
    for (int s = 64; s > 0; s >>= 1) {
        if (d < s) red[d] += red[d + s];
        __syncthreads();
    }
    float prob = sigmoidf_(red[0] + cls_b[0]);
    float obj_p = vj ? sub_p * prob : 0.f;

    if (t == 0) {
        feat_out[((size_t)b * DEG + rem) * D_DIM + d] = trans * obj_p;
        if (d == 0) {
            obj_out[b * DEG + rem] = obj;
            p_out[b * DEG + rem] = obj_p;
        }
    } else if (d == 0 && obj_p != 0.f) {
        atomicAdd(&e_out[(size_t)b * E_ENT + obj], obj_p);
    }
}

// last_e = last_e / max(last_e, 1)
__global__ void norm_kernel(float* __restrict__ e) {
    int i = blockIdx.x * blockDim.x + threadIdx.x;
    if (i < BSZ * E_ENT) {
        float v = e[i];
        e[i] = v / (v > 1.0f ? v : 1.0f);
    }
}

extern "C" void kernel_launch(void* const* d_in, const int* in_sizes, int n_in,
                              void* d_out, int out_size, void* d_ws, size_t ws_size,
                              hipStream_t stream) {
    const float* start    = (const float*)d_in[0];
    const float* rel_emb  = (const float*)d_in[1];
    const float* step_W   = (const float*)d_in[2];
    const float* step_b   = (const float*)d_in[3];
    const float* W_ih     = (const float*)d_in[4];
    const float* W_hh     = (const float*)d_in[5];
    const float* b_ih     = (const float*)d_in[6];
    const float* b_hh     = (const float*)d_in[7];
    const float* cls_w    = (const float*)d_in[8];
    const float* cls_b    = (const float*)d_in[9];
    const int*   query    = (const int*)d_in[10];
    const int*   kb_triple = (const int*)d_in[11];
    const int*   kb_range  = (const int*)d_in[12];
    float* out = (float*)d_out;

    char* ws = (char*)d_ws;
    float* WT_ih = (float*)ws;  ws += (size_t)D3 * D_DIM * sizeof(float);
    float* WT_hh = (float*)ws;  ws += (size_t)D3 * D_DIM * sizeof(float);
    float* cq    = (float*)ws;  ws += (size_t)2 * BSZ * D_DIM * sizeof(float);
    float* feat  = (float*)ws;  ws += (size_t)BSZ * DEG * D_DIM * sizeof(float);
    int*   objs  = (int*)ws;    ws += (size_t)BSZ * DEG * sizeof(int);
    float* p0    = (float*)ws;  ws += (size_t)BSZ * DEG * sizeof(float);
    ull*   keysA = (ull*)ws;    ws += (size_t)BSZ * NCH * K_TOP * sizeof(ull);
    int*   idx0  = (int*)ws;    ws += (size_t)BSZ * K_TOP * sizeof(int);
    float* val0  = (float*)ws;  ws += (size_t)BSZ * K_TOP * sizeof(float);
    int*   idx1  = (int*)ws;    ws += (size_t)BSZ * K_TOP * sizeof(int);
    float* val1  = (float*)ws;  ws += (size_t)BSZ * K_TOP * sizeof(float);

    transpose_kernel<<<(D3 * D_DIM + 255) / 256, 256, 0, stream>>>(W_ih, W_hh, WT_ih, WT_hh);
    cq_kernel<<<2 * BSZ, D_DIM, 0, stream>>>(rel_emb, step_W, step_b, query, cq);

    // ---- step 0: dense top-3 of start (two-stage), sparse outputs only ----
    topk_stageA<<<BSZ * NCH, 256, 0, stream>>>(start, keysA);
    topk_stageB<<<BSZ, 128, 0, stream>>>(keysA, idx0, val0);
    step_kernel<<<BSZ * DEG, D_DIM, 0, stream>>>(
        0, 1, idx0, val0, cq, rel_emb, kb_triple, kb_range,
        WT_ih, WT_hh, b_ih, b_hh, cls_w, cls_b,
        nullptr, nullptr, feat, objs, p0, nullptr);

    // ---- step 1: candidate top-3 from step-0 records, dense scatter + norm ----
    cand_topk<<<BSZ, DEG, 0, stream>>>(objs, p0, idx1, val1);
    hipMemsetAsync(d_out, 0, (size_t)BSZ * E_ENT * sizeof(float), stream);
    step_kernel<<<BSZ * K_TOP * DEG, D_DIM, 0, stream>>>(
        1, K_TOP, idx1, val1, cq + BSZ * D_DIM, rel_emb, kb_triple, kb_range,
        WT_ih, WT_hh, b_ih, b_hh, cls_w, cls_b,
        feat, objs, nullptr, nullptr, nullptr, out);
    norm_kernel<<<(BSZ * E_ENT + 255) / 256, 256, 0, stream>>>(out);
}